// Round 6
// baseline (281.067 us; speedup 1.0000x reference)
//
#include <hip/hip_runtime.h>
#include <hip/hip_bf16.h>

#define N_NODES 100000
#define NBUCKET 250
#define BUCKET_W 400              // nodes per dst-bucket (N_NODES/NBUCKET exact)
#define BK_EPT 14                 // edges per thread in bucket pass
#define GFP8_GRID (((N_NODES + 255) / 256) * 8)   // 391 node-tiles x 8 q-slices

typedef __attribute__((ext_vector_type(8))) short short8;     // 8 bf16 (4 VGPRs)
typedef __attribute__((ext_vector_type(8))) unsigned short u16x8;
typedef __attribute__((ext_vector_type(4))) unsigned short u16x4;
typedef __attribute__((ext_vector_type(4))) float floatx4;
typedef __attribute__((ext_vector_type(2))) float floatx2;

__device__ __forceinline__ float b2f(unsigned short u) {
    return __uint_as_float(((unsigned int)u) << 16);
}
__device__ __forceinline__ unsigned short f2b(float f) {   // RNE
    unsigned int u = __float_as_uint(f);
    unsigned int r = u + 0x7FFFu + ((u >> 16) & 1u);
    return (unsigned short)(r >> 16);
}

// ===========================================================================
// Fused prep: x->bf16 (node-major) + x->fp8 e4m3 (R14: q-major, i.e.
// xq[8][N][16B] feature-slice-major so each XCD's gather slice is a
// contiguous 1.6 MB L2-resident region) | weight swizzle | cursor init.
__global__ __launch_bounds__(256) void prep_kernel(
    const float* __restrict__ x,
    const float* __restrict__ W1l, const float* __restrict__ W1r,
    const float* __restrict__ W2l, const float* __restrict__ W2r,
    unsigned short* __restrict__ xb, unsigned char* __restrict__ xq,
    unsigned short* __restrict__ Wc1f,
    unsigned short* __restrict__ W2lf, unsigned short* __restrict__ W2rf,
    int* __restrict__ bucketCursor, int pairCap)
{
    int blk = blockIdx.x;
    if (blk < 12500) {
        int tid = blk * 256 + threadIdx.x;          // one float4 per thread
        float4 v = ((const float4*)x)[tid];
        u16x4 o;
        o.x = f2b(v.x); o.y = f2b(v.y); o.z = f2b(v.z); o.w = f2b(v.w);
        ((u16x4*)xb)[tid] = o;
        // fp8 pack: 4 floats -> 4 bytes, q-major slice layout
        int node = tid >> 5;                        // 32 float4 per 128-f row
        int j = tid & 31;                           // float4 index in row
        int p = 0;
        p = __builtin_amdgcn_cvt_pk_fp8_f32(v.x, v.y, p, false);  // bytes 0,1
        p = __builtin_amdgcn_cvt_pk_fp8_f32(v.z, v.w, p, true);   // bytes 2,3
        // slice q = j>>2 (16 features each), uint offset (j&3) within 16B row
        ((unsigned int*)xq)[((size_t)(j >> 2) * N_NODES + node) * 4 + (j & 3)] =
            (unsigned int)p;
    } else if (blk < 12692) {
        int tid = (blk - 12500) * 256 + threadIdx.x;
        if (tid < 32768) {                 // 8 ks * 8 t * 64 lane * 8 j
            int j = tid & 7, lane = (tid >> 3) & 63, t = (tid >> 9) & 7, ks = tid >> 12;
            int m = lane & 15, quad = lane >> 4;
            int row = t * 16 + m;
            int k = ks * 32 + quad * 8 + j;
            float v = (k < 128) ? W1l[row * 128 + k] : W1r[row * 128 + (k - 128)];
            Wc1f[tid] = f2b(v);
        } else if (tid < 40960) {          // 4 ks * 4 t * 64 lane * 8 j
            int idx = tid - 32768;
            int j = idx & 7, lane = (idx >> 3) & 63, t = (idx >> 9) & 3, ks = idx >> 11;
            int m = lane & 15, quad = lane >> 4;
            int row = t * 16 + m;
            int k = ks * 32 + quad * 8 + j;
            W2lf[idx] = f2b(W2l[row * 128 + k]);
        } else if (tid < 49152) {
            int idx = tid - 40960;
            int j = idx & 7, lane = (idx >> 3) & 63, t = (idx >> 9) & 3, ks = idx >> 11;
            int m = lane & 15, quad = lane >> 4;
            int row = t * 16 + m;
            int k = ks * 32 + quad * 8 + j;
            W2rf[idx] = f2b(W2r[row * 128 + k]);
        }
    } else {
        if (threadIdx.x < NBUCKET)
            bucketCursor[threadIdx.x] = threadIdx.x * pairCap;
    }
}

// ===========================================================================
// Pass 1: bucket edges into fixed-capacity per-bucket regions of pairs[].
__global__ __launch_bounds__(1024) void bucket_kernel(
    const int* __restrict__ src, const int* __restrict__ dst,
    int* __restrict__ bucketCursor, int2* __restrict__ pairs, int E)
{
    __shared__ int cnt[NBUCKET];
    __shared__ int base[NBUCKET];
    const int EPB = 1024 * BK_EPT;
    int e0 = blockIdx.x * EPB;
    for (int t = threadIdx.x; t < NBUCKET; t += 1024) cnt[t] = 0;
    __syncthreads();

    int es[BK_EPT], ed[BK_EPT], rk[BK_EPT], bk[BK_EPT];
    #pragma unroll
    for (int j = 0; j < BK_EPT; j++) {
        int i = e0 + j * 1024 + threadIdx.x;
        if (i < E) {
            es[j] = src[i];
            ed[j] = dst[i];
            bk[j] = ed[j] / BUCKET_W;
            rk[j] = atomicAdd(&cnt[bk[j]], 1);
        } else {
            bk[j] = -1;
        }
    }
    __syncthreads();
    for (int t = threadIdx.x; t < NBUCKET; t += 1024)
        base[t] = atomicAdd(&bucketCursor[t], cnt[t]);
    __syncthreads();

    #pragma unroll
    for (int j = 0; j < BK_EPT; j++) {
        if (bk[j] >= 0)
            pairs[(size_t)base[bk[j]] + rk[j]] = make_int2(es[j], ed[j]);
    }
}

// ===========================================================================
// Pass 2 (R8 single placement pass, worklist of R13 reverted — it cut
// divergence but destroyed edge_src/aggOut locality, net regression).
__global__ __launch_bounds__(1024) void fill_kernel(
    const int2* __restrict__ pairs, const int* __restrict__ bucketCursor,
    int* __restrict__ edge_src, int2* __restrict__ nodeInfo, int pairCap)
{
    __shared__ int hist[BUCKET_W];
    __shared__ int off[BUCKET_W];
    __shared__ int cur[BUCKET_W];
    int b = blockIdx.x;
    int t = threadIdx.x;
    int base = b * pairCap;
    int cnt = bucketCursor[b] - base;
    int node0 = b * BUCKET_W;

    if (t < BUCKET_W) hist[t] = 0;
    __syncthreads();
    for (int i = t; i < cnt; i += 1024)
        atomicAdd(&hist[pairs[base + i].y - node0], 1);
    __syncthreads();

    if (t < BUCKET_W) off[t] = hist[t];
    __syncthreads();
    for (int o = 1; o < BUCKET_W; o <<= 1) {
        int v = 0;
        if (t < BUCKET_W && t >= o) v = off[t - o];
        __syncthreads();
        if (t < BUCKET_W && t >= o) off[t] += v;
        __syncthreads();
    }
    if (t < BUCKET_W) {
        int gb = base + off[t] - hist[t];     // exclusive prefix
        cur[t] = gb;
        nodeInfo[node0 + t] = make_int2(gb, hist[t]);
    }
    __syncthreads();

    for (int i = t; i < cnt; i += 1024) {
        int2 p = pairs[base + i];
        int pos = atomicAdd(&cur[p.y - node0], 1);
        edge_src[pos] = p.x;
    }
}

// ===========================================================================
// Layer-1 gather (R14: XCD-sliced). Block handles 256 nodes x ONE 16-feature
// slice q = blockIdx.x & 7; round-robin block->XCD dispatch means each XCD
// only touches its own 1.6 MB slice of the q-major fp8 table -> L2-resident,
// random reads become L2 hits instead of 3.4 TB/s-capped HBM fills.
// Per-lane work identical to R4 (same trip count, same ACC16).
__global__ __launch_bounds__(256) void gather_fp8_kernel(
    const unsigned char* __restrict__ xq, const int* __restrict__ edge_src,
    const int2* __restrict__ nodeInfo, unsigned short* __restrict__ aggOut)
{
    int q = blockIdx.x & 7;
    int node = (blockIdx.x >> 3) * 256 + threadIdx.x;
    if (node >= N_NODES) return;
    int2 info = nodeInfo[node];
    int e = info.x, deg = info.y, end = info.x + deg;
    const uint4* f16 = (const uint4*)xq + (size_t)q * N_NODES;  // one uint4/row

    float acc[16];
    #pragma unroll
    for (int j = 0; j < 16; j++) acc[j] = 0.0f;

    #define ACC16(W)  do {                                                   \
        floatx2 p;                                                           \
        p = __builtin_amdgcn_cvt_pk_f32_fp8((W).x, false); acc[0]+=p.x; acc[1]+=p.y;  \
        p = __builtin_amdgcn_cvt_pk_f32_fp8((W).x, true);  acc[2]+=p.x; acc[3]+=p.y;  \
        p = __builtin_amdgcn_cvt_pk_f32_fp8((W).y, false); acc[4]+=p.x; acc[5]+=p.y;  \
        p = __builtin_amdgcn_cvt_pk_f32_fp8((W).y, true);  acc[6]+=p.x; acc[7]+=p.y;  \
        p = __builtin_amdgcn_cvt_pk_f32_fp8((W).z, false); acc[8]+=p.x; acc[9]+=p.y;  \
        p = __builtin_amdgcn_cvt_pk_f32_fp8((W).z, true);  acc[10]+=p.x; acc[11]+=p.y;\
        p = __builtin_amdgcn_cvt_pk_f32_fp8((W).w, false); acc[12]+=p.x; acc[13]+=p.y;\
        p = __builtin_amdgcn_cvt_pk_f32_fp8((W).w, true);  acc[14]+=p.x; acc[15]+=p.y;\
    } while (0)

    for (; e + 4 <= end; e += 4) {
        int s0 = edge_src[e + 0];
        int s1 = edge_src[e + 1];
        int s2 = edge_src[e + 2];
        int s3 = edge_src[e + 3];
        uint4 w0 = f16[s0];
        uint4 w1 = f16[s1];
        uint4 w2 = f16[s2];
        uint4 w3 = f16[s3];
        ACC16(w0); ACC16(w1); ACC16(w2); ACC16(w3);
    }
    for (; e < end; e++) {
        uint4 w0 = f16[edge_src[e]];
        ACC16(w0);
    }
    #undef ACC16

    float inv = (deg > 0) ? 1.0f / (float)deg : 0.0f;
    u16x8 o0, o1;
    #pragma unroll
    for (int j = 0; j < 8; j++) { o0[j] = f2b(acc[j] * inv); o1[j] = f2b(acc[8 + j] * inv); }
    // a1b is q-major too: [8][N][16 shorts]; consecutive lanes -> consecutive
    // 32 B rows -> fully coalesced.
    u16x8* op = (u16x8*)(aggOut + ((size_t)q * N_NODES + node) * 16);
    op[0] = o0;
    op[1] = o1;
}

// ===========================================================================
// Fused dense block (fragment-major weights, 32 nodes/wave).
// R9: deep register prefetch. R10: fp8 pi-layout outputs.
// R14: a1b is q-major [8][N][16]; fragment (ks<4, features ks*32+quad*8..+7)
// maps to slice q = ks*2+(quad>>1), short offset (quad&1)*8 — verified
// ks*32+quad*8 == q*16 + rem for quad 0..3.
__global__ __launch_bounds__(256, 2) void fused_l1_kernel(
    const unsigned short* __restrict__ a1b, const unsigned short* __restrict__ xb,
    const unsigned short* __restrict__ Wc1f, const float* __restrict__ b1,
    const unsigned short* __restrict__ W2lf, const unsigned short* __restrict__ W2rf,
    unsigned char* __restrict__ g2q, unsigned short* __restrict__ r2b)
{
    __shared__ unsigned short h_lds[4][32][136];

    int wave = threadIdx.x >> 6;
    int lane = threadIdx.x & 63;
    int m    = lane & 15;
    int quad = lane >> 4;
    int node0 = blockIdx.x * 128 + wave * 32;

    int n0 = min(node0 + m,      N_NODES - 1);
    int n1 = min(node0 + 16 + m, N_NODES - 1);

    // ---- Layer 1: prefetch ALL 16 A-fragments (64 VGPRs, 16 loads in flight)
    short8 a0[8], a1[8];
    #pragma unroll
    for (int ks = 0; ks < 8; ks++) {
        if (ks < 4) {
            int q   = ks * 2 + (quad >> 1);
            int rem = (quad & 1) * 8;
            a0[ks] = *(const short8*)(a1b + ((size_t)q * N_NODES + n0) * 16 + rem);
            a1[ks] = *(const short8*)(a1b + ((size_t)q * N_NODES + n1) * 16 + rem);
        } else {
            int koff = ks * 32 + quad * 8 - 128;
            a0[ks] = *(const short8*)(xb + (size_t)n0 * 128 + koff);
            a1[ks] = *(const short8*)(xb + (size_t)n1 * 128 + koff);
        }
    }

    floatx4 acc[2][8];
    #pragma unroll
    for (int mt = 0; mt < 2; mt++)
        #pragma unroll
        for (int t = 0; t < 8; t++) acc[mt][t] = (floatx4)(0.0f);

    // B fragments: double-buffered, prefetched one ks-step ahead.
    const unsigned short* Wp = Wc1f + (lane << 3);
    short8 bb[2][8];
    #pragma unroll
    for (int t = 0; t < 8; t++)
        bb[0][t] = *(const short8*)(Wp + ((t * 64) << 3));

    #pragma unroll
    for (int ks = 0; ks < 8; ks++) {
        if (ks < 7) {
            #pragma unroll
            for (int t = 0; t < 8; t++)
                bb[(ks + 1) & 1][t] =
                    *(const short8*)(Wp + ((((ks + 1) * 8 + t) * 64) << 3));
        }
        #pragma unroll
        for (int t = 0; t < 8; t++) {
            acc[0][t] = __builtin_amdgcn_mfma_f32_16x16x32_bf16(a0[ks], bb[ks & 1][t], acc[0][t], 0, 0, 0);
            acc[1][t] = __builtin_amdgcn_mfma_f32_16x16x32_bf16(a1[ks], bb[ks & 1][t], acc[1][t], 0, 0, 0);
        }
    }

    #pragma unroll
    for (int t = 0; t < 8; t++) {
        int j = t * 16 + m;
        float bias = b1[j];
        #pragma unroll
        for (int mt = 0; mt < 2; mt++) {
            #pragma unroll
            for (int r = 0; r < 4; r++) {
                int row = mt * 16 + quad * 4 + r;
                h_lds[wave][row][j] = f2b(fmaxf(acc[mt][t][r] + bias, 0.0f));
            }
        }
    }
    // h_lds[wave] is wave-private — per-wave LDS drain instead of barrier.
    asm volatile("s_waitcnt lgkmcnt(0)" ::: "memory");

    // ---- Layer 2: load all 8 h-fragments from LDS, double-buffer W2 loads.
    short8 h0[4], h1[4];
    #pragma unroll
    for (int ks = 0; ks < 4; ks++) {
        int k0 = ks * 32 + quad * 8;
        h0[ks] = *(const short8*)&h_lds[wave][m][k0];
        h1[ks] = *(const short8*)&h_lds[wave][16 + m][k0];
    }

    floatx4 acc2[2][4], acc3[2][4];
    #pragma unroll
    for (int mt = 0; mt < 2; mt++)
        #pragma unroll
        for (int t = 0; t < 4; t++) { acc2[mt][t] = (floatx4)(0.0f); acc3[mt][t] = (floatx4)(0.0f); }

    const unsigned short* W2lp = W2lf + (lane << 3);
    const unsigned short* W2rp = W2rf + (lane << 3);
    short8 bl2[2][4], br2[2][4];
    #pragma unroll
    for (int t = 0; t < 4; t++) {
        bl2[0][t] = *(const short8*)(W2lp + ((t * 64) << 3));
        br2[0][t] = *(const short8*)(W2rp + ((t * 64) << 3));
    }

    #pragma unroll
    for (int ks = 0; ks < 4; ks++) {
        if (ks < 3) {
            #pragma unroll
            for (int t = 0; t < 4; t++) {
                bl2[(ks + 1) & 1][t] = *(const short8*)(W2lp + ((((ks + 1) * 4 + t) * 64) << 3));
                br2[(ks + 1) & 1][t] = *(const short8*)(W2rp + ((((ks + 1) * 4 + t) * 64) << 3));
            }
        }
        #pragma unroll
        for (int t = 0; t < 4; t++) {
            acc2[0][t] = __builtin_amdgcn_mfma_f32_16x16x32_bf16(h0[ks], bl2[ks & 1][t], acc2[0][t], 0, 0, 0);
            acc2[1][t] = __builtin_amdgcn_mfma_f32_16x16x32_bf16(h1[ks], bl2[ks & 1][t], acc2[1][t], 0, 0, 0);
            acc3[0][t] = __builtin_amdgcn_mfma_f32_16x16x32_bf16(h0[ks], br2[ks & 1][t], acc3[0][t], 0, 0, 0);
            acc3[1][t] = __builtin_amdgcn_mfma_f32_16x16x32_bf16(h1[ks], br2[ks & 1][t], acc3[1][t], 0, 0, 0);
        }
    }

    // pi-layout epilogue: lane (m) owns byte/short positions m*4 + t of each
    // of its 8 rows. g2q: one u32 store (4 fp8). r2b: one u16x4 store.
    #pragma unroll
    for (int mt = 0; mt < 2; mt++) {
        #pragma unroll
        for (int r = 0; r < 4; r++) {
            int n = node0 + mt * 16 + quad * 4 + r;
            if (n < N_NODES) {
                int p = 0;
                p = __builtin_amdgcn_cvt_pk_fp8_f32(acc2[mt][0][r], acc2[mt][1][r], p, false);
                p = __builtin_amdgcn_cvt_pk_fp8_f32(acc2[mt][2][r], acc2[mt][3][r], p, true);
                *(unsigned int*)(g2q + (size_t)n * 64 + m * 4) = (unsigned int)p;
                u16x4 rb;
                rb.x = f2b(acc3[mt][0][r]);
                rb.y = f2b(acc3[mt][1][r]);
                rb.z = f2b(acc3[mt][2][r]);
                rb.w = f2b(acc3[mt][3][r]);
                *(u16x4*)(r2b + (size_t)n * 64 + m * 4) = rb;
            }
        }
    }
}

// ===========================================================================
// Layer-2 gather (fp8 rows, 64 B/edge) fused with bias + residual +
// log_softmax. Rows in pi-layout; lane q reads bytes q*8..q*8+7 = cols
// {16t+2q, 16t+2q+1}. Un-permuted at the final store. (Worklist reverted.)
__global__ __launch_bounds__(256) void gather_final_kernel(
    const unsigned char* __restrict__ g2q, const int* __restrict__ edge_src,
    const int2* __restrict__ nodeInfo, const unsigned short* __restrict__ r2b,
    const float* __restrict__ b2, float* __restrict__ out)
{
    int tid = blockIdx.x * 256 + threadIdx.x;
    int node = tid >> 3;
    int q = tid & 7;
    int2 info = nodeInfo[node];
    int e = info.x, deg = info.y, end = info.x + deg;
    const uint2* f8 = (const uint2*)g2q;      // 8 fp8 per uint2; row = 8 uint2
    float acc[8];
    #pragma unroll
    for (int j = 0; j < 8; j++) acc[j] = 0.0f;

    #define ACC8(W)  do {                                                    \
        floatx2 p;                                                           \
        p = __builtin_amdgcn_cvt_pk_f32_fp8((W).x, false); acc[0]+=p.x; acc[1]+=p.y; \
        p = __builtin_amdgcn_cvt_pk_f32_fp8((W).x, true);  acc[2]+=p.x; acc[3]+=p.y; \
        p = __builtin_amdgcn_cvt_pk_f32_fp8((W).y, false); acc[4]+=p.x; acc[5]+=p.y; \
        p = __builtin_amdgcn_cvt_pk_f32_fp8((W).y, true);  acc[6]+=p.x; acc[7]+=p.y; \
    } while (0)

    for (; e + 4 <= end; e += 4) {
        int s0 = edge_src[e + 0];
        int s1 = edge_src[e + 1];
        int s2 = edge_src[e + 2];
        int s3 = edge_src[e + 3];
        uint2 v0 = f8[(size_t)s0 * 8 + q];
        uint2 v1 = f8[(size_t)s1 * 8 + q];
        uint2 v2 = f8[(size_t)s2 * 8 + q];
        uint2 v3 = f8[(size_t)s3 * 8 + q];
        ACC8(v0); ACC8(v1); ACC8(v2); ACC8(v3);
    }
    for (; e < end; e++) {
        uint2 v0 = f8[(size_t)edge_src[e] * 8 + q];
        ACC8(v0);
    }
    #undef ACC8

    float inv = (deg > 0) ? 1.0f / (float)deg : 0.0f;

    // residual: r2b is in the same pi-layout -> contiguous u16x8 per lane
    u16x8 rv = ((const u16x8*)r2b)[tid];            // node*64 + q*8 .. +7

    // bias for position q*8+j: col = 16*(j&3) + 2q + (j>>2)
    float2 bb0 = *(const float2*)(b2 + 0  + 2 * q);
    float2 bb1 = *(const float2*)(b2 + 16 + 2 * q);
    float2 bb2 = *(const float2*)(b2 + 32 + 2 * q);
    float2 bb3 = *(const float2*)(b2 + 48 + 2 * q);

    float v[8];
    v[0] = acc[0] * inv + bb0.x + b2f(rv[0]);
    v[1] = acc[1] * inv + bb1.x + b2f(rv[1]);
    v[2] = acc[2] * inv + bb2.x + b2f(rv[2]);
    v[3] = acc[3] * inv + bb3.x + b2f(rv[3]);
    v[4] = acc[4] * inv + bb0.y + b2f(rv[4]);
    v[5] = acc[5] * inv + bb1.y + b2f(rv[5]);
    v[6] = acc[6] * inv + bb2.y + b2f(rv[6]);
    v[7] = acc[7] * inv + bb3.y + b2f(rv[7]);

    float mx = v[0];
    #pragma unroll
    for (int j = 1; j < 8; j++) mx = fmaxf(mx, v[j]);
    mx = fmaxf(mx, __shfl_xor(mx, 1, 64));
    mx = fmaxf(mx, __shfl_xor(mx, 2, 64));
    mx = fmaxf(mx, __shfl_xor(mx, 4, 64));
    float s = 0.0f;
    #pragma unroll
    for (int j = 0; j < 8; j++) s += expf(v[j] - mx);
    s += __shfl_xor(s, 1, 64);
    s += __shfl_xor(s, 2, 64);
    s += __shfl_xor(s, 4, 64);
    float lg = mx + logf(s);

    // un-permute: v[t], v[t+4] are cols 16t+2q, 16t+2q+1 -> float2 stores
    float* ob = out + (size_t)node * 64 + 2 * q;
    *(float2*)(ob + 0)  = make_float2(v[0] - lg, v[4] - lg);
    *(float2*)(ob + 16) = make_float2(v[1] - lg, v[5] - lg);
    *(float2*)(ob + 32) = make_float2(v[2] - lg, v[6] - lg);
    *(float2*)(ob + 48) = make_float2(v[3] - lg, v[7] - lg);
}

// ===========================================================================
extern "C" void kernel_launch(void* const* d_in, const int* in_sizes, int n_in,
                              void* d_out, int out_size, void* d_ws, size_t ws_size,
                              hipStream_t stream)
{
    const float* x   = (const float*)d_in[0];
    const int*   ei  = (const int*)d_in[1];
    const float* W1l = (const float*)d_in[2];
    const float* b1  = (const float*)d_in[3];
    const float* W1r = (const float*)d_in[4];
    const float* W2l = (const float*)d_in[5];
    const float* b2  = (const float*)d_in[6];
    const float* W2r = (const float*)d_in[7];
    float* out = (float*)d_out;

    int E = in_sizes[1] / 2;
    const int* src = ei;
    const int* dst = ei + E;

    // Per-bucket pair capacity: 1.5x mean (mean 6400, sigma 80 -> +40 sigma).
    int pairCap = ((E / NBUCKET) * 3 / 2 + 255) / 256 * 256;   // 9600 for E=1.6M

    // Workspace layout (16B-aligned sections)
    char* ws = (char*)d_ws;
    int*  bucketCursor = (int*)ws;   ws += ((size_t)NBUCKET * 4 + 15) / 16 * 16;
    int2* pairs        = (int2*)ws;  ws += (size_t)NBUCKET * pairCap * 8;
    int*  edge_src     = (int*)ws;   ws += (size_t)NBUCKET * pairCap * 4;
    int2* nodeInfo     = (int2*)ws;  ws += (size_t)N_NODES * 8;
    unsigned short* xb   = (unsigned short*)ws;  ws += (size_t)N_NODES * 128 * 2;
    unsigned char*  xq   = (unsigned char*)ws;   ws += (size_t)N_NODES * 128;
    unsigned short* a1b  = (unsigned short*)ws;  ws += (size_t)N_NODES * 128 * 2;
    unsigned char*  g2q  = (unsigned char*)ws;   ws += (size_t)N_NODES * 64;
    unsigned short* r2b  = (unsigned short*)ws;  ws += (size_t)N_NODES * 64 * 2;
    unsigned short* Wc1f = (unsigned short*)ws;  ws += 128 * 256 * 2;
    unsigned short* W2lf = (unsigned short*)ws;  ws += 64 * 128 * 2;
    unsigned short* W2rf = (unsigned short*)ws;  ws += 64 * 128 * 2;

    // 1. prep: bf16 + q-major fp8 casts + weight swizzle + cursor init
    prep_kernel<<<12693, 256, 0, stream>>>(
        x, W1l, W1r, W2l, W2r, xb, xq, Wc1f, W2lf, W2rf, bucketCursor, pairCap);

    // 2. bucket edges by dst range (block-exclusive chunk writes)
    {
        const int EPB = 1024 * BK_EPT;
        bucket_kernel<<<(E + EPB - 1) / EPB, 1024, 0, stream>>>(
            src, dst, bucketCursor, pairs, E);
    }

    // 3. per-bucket LDS hist/scan/place -> edge_src + nodeInfo (beg,deg)
    fill_kernel<<<NBUCKET, 1024, 0, stream>>>(
        pairs, bucketCursor, edge_src, nodeInfo, pairCap);

    // 4. layer-1 aggregation, XCD-sliced: block = 256 nodes x 1 q-slice;
    //    q = blockIdx & 7 rides the round-robin block->XCD dispatch.
    gather_fp8_kernel<<<GFP8_GRID, 256, 0, stream>>>(
        xq, edge_src, nodeInfo, a1b);

    // 5. fused dense block: layer1 GEMM + relu + both layer2 matmuls
    fused_l1_kernel<<<(N_NODES + 127) / 128, 256, 0, stream>>>(
        a1b, xb, Wc1f, b1, W2lf, W2rf, g2q, r2b);

    // 6. layer-2 aggregation (fp8) fused with bias + residual + log_softmax
    gather_final_kernel<<<(N_NODES * 8) / 256, 256, 0, stream>>>(
        g2q, edge_src, nodeInfo, r2b, b2, out);
}

// Round 7
// 263.194 us; speedup vs baseline: 1.0679x; 1.0679x over previous
//
#include <hip/hip_runtime.h>
#include <hip/hip_bf16.h>

#define N_NODES 100000
#define NBUCKET 250
#define BUCKET_W 400              // nodes per dst-bucket (N_NODES/NBUCKET exact)
#define BK_EPT 14                 // edges per thread in bucket pass
#define GFP8_GRID (((N_NODES + 255) / 256) * 8)   // 391 tile-pairs x (4 slice x 2 half)

typedef __attribute__((ext_vector_type(8))) short short8;     // 8 bf16 (4 VGPRs)
typedef __attribute__((ext_vector_type(8))) unsigned short u16x8;
typedef __attribute__((ext_vector_type(4))) unsigned short u16x4;
typedef __attribute__((ext_vector_type(4))) float floatx4;
typedef __attribute__((ext_vector_type(2))) float floatx2;

__device__ __forceinline__ float b2f(unsigned short u) {
    return __uint_as_float(((unsigned int)u) << 16);
}
__device__ __forceinline__ unsigned short f2b(float f) {   // RNE
    unsigned int u = __float_as_uint(f);
    unsigned int r = u + 0x7FFFu + ((u >> 16) & 1u);
    return (unsigned short)(r >> 16);
}

// ===========================================================================
// Fused prep: x->bf16 (node-major) + x->fp8 e4m3 (R15: 4 slices of 32
// features, xq[4][N][32B] — each slice 3.2 MB, L2-resident per XCD, and a
// node's 32-B row lives in ONE 64-B line) | weight swizzle | cursor init.
__global__ __launch_bounds__(256) void prep_kernel(
    const float* __restrict__ x,
    const float* __restrict__ W1l, const float* __restrict__ W1r,
    const float* __restrict__ W2l, const float* __restrict__ W2r,
    unsigned short* __restrict__ xb, unsigned char* __restrict__ xq,
    unsigned short* __restrict__ Wc1f,
    unsigned short* __restrict__ W2lf, unsigned short* __restrict__ W2rf,
    int* __restrict__ bucketCursor, int pairCap)
{
    int blk = blockIdx.x;
    if (blk < 12500) {
        int tid = blk * 256 + threadIdx.x;          // one float4 per thread
        float4 v = ((const float4*)x)[tid];
        u16x4 o;
        o.x = f2b(v.x); o.y = f2b(v.y); o.z = f2b(v.z); o.w = f2b(v.w);
        ((u16x4*)xb)[tid] = o;
        // fp8 pack: 4 floats -> 4 bytes (1 uint), 32-B slice layout
        int node = tid >> 5;                        // 32 float4 per 128-f row
        int j = tid & 31;                           // float4 index in row
        int p = 0;
        p = __builtin_amdgcn_cvt_pk_fp8_f32(v.x, v.y, p, false);  // bytes 0,1
        p = __builtin_amdgcn_cvt_pk_fp8_f32(v.z, v.w, p, true);   // bytes 2,3
        // slice = j>>3 (32 features each), uint (j&7) within the 32-B row
        ((unsigned int*)xq)[((size_t)(j >> 3) * N_NODES + node) * 8 + (j & 7)] =
            (unsigned int)p;
    } else if (blk < 12692) {
        int tid = (blk - 12500) * 256 + threadIdx.x;
        if (tid < 32768) {                 // 8 ks * 8 t * 64 lane * 8 j
            int j = tid & 7, lane = (tid >> 3) & 63, t = (tid >> 9) & 7, ks = tid >> 12;
            int m = lane & 15, quad = lane >> 4;
            int row = t * 16 + m;
            int k = ks * 32 + quad * 8 + j;
            float v = (k < 128) ? W1l[row * 128 + k] : W1r[row * 128 + (k - 128)];
            Wc1f[tid] = f2b(v);
        } else if (tid < 40960) {          // 4 ks * 4 t * 64 lane * 8 j
            int idx = tid - 32768;
            int j = idx & 7, lane = (idx >> 3) & 63, t = (idx >> 9) & 3, ks = idx >> 11;
            int m = lane & 15, quad = lane >> 4;
            int row = t * 16 + m;
            int k = ks * 32 + quad * 8 + j;
            W2lf[idx] = f2b(W2l[row * 128 + k]);
        } else if (tid < 49152) {
            int idx = tid - 40960;
            int j = idx & 7, lane = (idx >> 3) & 63, t = (idx >> 9) & 3, ks = idx >> 11;
            int m = lane & 15, quad = lane >> 4;
            int row = t * 16 + m;
            int k = ks * 32 + quad * 8 + j;
            W2rf[idx] = f2b(W2r[row * 128 + k]);
        }
    } else {
        if (threadIdx.x < NBUCKET)
            bucketCursor[threadIdx.x] = threadIdx.x * pairCap;
    }
}

// ===========================================================================
// Pass 1: bucket edges into fixed-capacity per-bucket regions of pairs[].
__global__ __launch_bounds__(1024) void bucket_kernel(
    const int* __restrict__ src, const int* __restrict__ dst,
    int* __restrict__ bucketCursor, int2* __restrict__ pairs, int E)
{
    __shared__ int cnt[NBUCKET];
    __shared__ int base[NBUCKET];
    const int EPB = 1024 * BK_EPT;
    int e0 = blockIdx.x * EPB;
    for (int t = threadIdx.x; t < NBUCKET; t += 1024) cnt[t] = 0;
    __syncthreads();

    int es[BK_EPT], ed[BK_EPT], rk[BK_EPT], bk[BK_EPT];
    #pragma unroll
    for (int j = 0; j < BK_EPT; j++) {
        int i = e0 + j * 1024 + threadIdx.x;
        if (i < E) {
            es[j] = src[i];
            ed[j] = dst[i];
            bk[j] = ed[j] / BUCKET_W;
            rk[j] = atomicAdd(&cnt[bk[j]], 1);
        } else {
            bk[j] = -1;
        }
    }
    __syncthreads();
    for (int t = threadIdx.x; t < NBUCKET; t += 1024)
        base[t] = atomicAdd(&bucketCursor[t], cnt[t]);
    __syncthreads();

    #pragma unroll
    for (int j = 0; j < BK_EPT; j++) {
        if (bk[j] >= 0)
            pairs[(size_t)base[bk[j]] + rk[j]] = make_int2(es[j], ed[j]);
    }
}

// ===========================================================================
// Pass 2 (R8 single placement pass). One block per bucket: LDS hist over 400
// nodes, LDS scan, LDS cursors -> edge_src + nodeInfo (beg,deg).
__global__ __launch_bounds__(1024) void fill_kernel(
    const int2* __restrict__ pairs, const int* __restrict__ bucketCursor,
    int* __restrict__ edge_src, int2* __restrict__ nodeInfo, int pairCap)
{
    __shared__ int hist[BUCKET_W];
    __shared__ int off[BUCKET_W];
    __shared__ int cur[BUCKET_W];
    int b = blockIdx.x;
    int t = threadIdx.x;
    int base = b * pairCap;
    int cnt = bucketCursor[b] - base;
    int node0 = b * BUCKET_W;

    if (t < BUCKET_W) hist[t] = 0;
    __syncthreads();
    for (int i = t; i < cnt; i += 1024)
        atomicAdd(&hist[pairs[base + i].y - node0], 1);
    __syncthreads();

    if (t < BUCKET_W) off[t] = hist[t];
    __syncthreads();
    for (int o = 1; o < BUCKET_W; o <<= 1) {
        int v = 0;
        if (t < BUCKET_W && t >= o) v = off[t - o];
        __syncthreads();
        if (t < BUCKET_W && t >= o) off[t] += v;
        __syncthreads();
    }
    if (t < BUCKET_W) {
        int gb = base + off[t] - hist[t];     // exclusive prefix
        cur[t] = gb;
        nodeInfo[node0 + t] = make_int2(gb, hist[t]);
    }
    __syncthreads();

    for (int i = t; i < cnt; i += 1024) {
        int2 p = pairs[base + i];
        int pos = atomicAdd(&cur[p.y - node0], 1);
        edge_src[pos] = p.x;
    }
}

// ===========================================================================
// Layer-1 gather (R15: 32-B XCD slices, 2 lanes/node). Block sub-id
// (blockIdx&7) = slice(2b) x half(1b): mod-8 XCD round-robin keeps each XCD
// on ONE 3.2 MB slice (L2-resident), while a node's 32-B row is read by a
// lane PAIR (16 B each) -> one 64-B line per node per edge (32 lines/wave,
// half of R14's 64; all L2 hits unlike R4's HBM fills).
__global__ __launch_bounds__(256) void gather_fp8_kernel(
    const unsigned char* __restrict__ xq, const int* __restrict__ edge_src,
    const int2* __restrict__ nodeInfo, unsigned short* __restrict__ aggOut)
{
    int tile  = blockIdx.x >> 3;
    int sub   = blockIdx.x & 7;
    int slice = sub >> 1;
    int half  = sub & 1;
    int node  = (tile * 2 + half) * 128 + (threadIdx.x >> 1);
    int part  = threadIdx.x & 1;
    if (node >= N_NODES) return;
    int2 info = nodeInfo[node];
    int e = info.x, deg = info.y, end = info.x + deg;
    // row of slice = 2 uint4; this lane owns uint4 #part of each row
    const uint4* f16 = (const uint4*)xq + (size_t)slice * N_NODES * 2 + part;

    float acc[16];
    #pragma unroll
    for (int j = 0; j < 16; j++) acc[j] = 0.0f;

    #define ACC16(W)  do {                                                   \
        floatx2 p;                                                           \
        p = __builtin_amdgcn_cvt_pk_f32_fp8((W).x, false); acc[0]+=p.x; acc[1]+=p.y;  \
        p = __builtin_amdgcn_cvt_pk_f32_fp8((W).x, true);  acc[2]+=p.x; acc[3]+=p.y;  \
        p = __builtin_amdgcn_cvt_pk_f32_fp8((W).y, false); acc[4]+=p.x; acc[5]+=p.y;  \
        p = __builtin_amdgcn_cvt_pk_f32_fp8((W).y, true);  acc[6]+=p.x; acc[7]+=p.y;  \
        p = __builtin_amdgcn_cvt_pk_f32_fp8((W).z, false); acc[8]+=p.x; acc[9]+=p.y;  \
        p = __builtin_amdgcn_cvt_pk_f32_fp8((W).z, true);  acc[10]+=p.x; acc[11]+=p.y;\
        p = __builtin_amdgcn_cvt_pk_f32_fp8((W).w, false); acc[12]+=p.x; acc[13]+=p.y;\
        p = __builtin_amdgcn_cvt_pk_f32_fp8((W).w, true);  acc[14]+=p.x; acc[15]+=p.y;\
    } while (0)

    for (; e + 4 <= end; e += 4) {
        int s0 = edge_src[e + 0];
        int s1 = edge_src[e + 1];
        int s2 = edge_src[e + 2];
        int s3 = edge_src[e + 3];
        uint4 w0 = f16[(size_t)s0 * 2];
        uint4 w1 = f16[(size_t)s1 * 2];
        uint4 w2 = f16[(size_t)s2 * 2];
        uint4 w3 = f16[(size_t)s3 * 2];
        ACC16(w0); ACC16(w1); ACC16(w2); ACC16(w3);
    }
    for (; e < end; e++) {
        uint4 w0 = f16[(size_t)edge_src[e] * 2];
        ACC16(w0);
    }
    #undef ACC16

    float inv = (deg > 0) ? 1.0f / (float)deg : 0.0f;
    u16x8 o0, o1;
    #pragma unroll
    for (int j = 0; j < 8; j++) { o0[j] = f2b(acc[j] * inv); o1[j] = f2b(acc[8 + j] * inv); }
    // a1b slice-major [4][N][32 shorts]; lane writes 32 B, pair writes 64 B.
    u16x8* op = (u16x8*)(aggOut + ((size_t)slice * N_NODES + node) * 32 + part * 16);
    op[0] = o0;
    op[1] = o1;
}

// ===========================================================================
// Fused dense block (fragment-major weights, 32 nodes/wave).
// R9: deep register prefetch. R10: fp8 pi-layout outputs.
// R15: a1b is slice-major [4][N][32]; fragment features ks*32+quad*8 (ks<4)
// == slice ks, short offset quad*8 — exact.
__global__ __launch_bounds__(256, 2) void fused_l1_kernel(
    const unsigned short* __restrict__ a1b, const unsigned short* __restrict__ xb,
    const unsigned short* __restrict__ Wc1f, const float* __restrict__ b1,
    const unsigned short* __restrict__ W2lf, const unsigned short* __restrict__ W2rf,
    unsigned char* __restrict__ g2q, unsigned short* __restrict__ r2b)
{
    __shared__ unsigned short h_lds[4][32][136];

    int wave = threadIdx.x >> 6;
    int lane = threadIdx.x & 63;
    int m    = lane & 15;
    int quad = lane >> 4;
    int node0 = blockIdx.x * 128 + wave * 32;

    int n0 = min(node0 + m,      N_NODES - 1);
    int n1 = min(node0 + 16 + m, N_NODES - 1);

    // ---- Layer 1: prefetch ALL 16 A-fragments (64 VGPRs, 16 loads in flight)
    short8 a0[8], a1[8];
    #pragma unroll
    for (int ks = 0; ks < 8; ks++) {
        if (ks < 4) {
            a0[ks] = *(const short8*)(a1b + ((size_t)ks * N_NODES + n0) * 32 + quad * 8);
            a1[ks] = *(const short8*)(a1b + ((size_t)ks * N_NODES + n1) * 32 + quad * 8);
        } else {
            int koff = ks * 32 + quad * 8 - 128;
            a0[ks] = *(const short8*)(xb + (size_t)n0 * 128 + koff);
            a1[ks] = *(const short8*)(xb + (size_t)n1 * 128 + koff);
        }
    }

    floatx4 acc[2][8];
    #pragma unroll
    for (int mt = 0; mt < 2; mt++)
        #pragma unroll
        for (int t = 0; t < 8; t++) acc[mt][t] = (floatx4)(0.0f);

    // B fragments: double-buffered, prefetched one ks-step ahead.
    const unsigned short* Wp = Wc1f + (lane << 3);
    short8 bb[2][8];
    #pragma unroll
    for (int t = 0; t < 8; t++)
        bb[0][t] = *(const short8*)(Wp + ((t * 64) << 3));

    #pragma unroll
    for (int ks = 0; ks < 8; ks++) {
        if (ks < 7) {
            #pragma unroll
            for (int t = 0; t < 8; t++)
                bb[(ks + 1) & 1][t] =
                    *(const short8*)(Wp + ((((ks + 1) * 8 + t) * 64) << 3));
        }
        #pragma unroll
        for (int t = 0; t < 8; t++) {
            acc[0][t] = __builtin_amdgcn_mfma_f32_16x16x32_bf16(a0[ks], bb[ks & 1][t], acc[0][t], 0, 0, 0);
            acc[1][t] = __builtin_amdgcn_mfma_f32_16x16x32_bf16(a1[ks], bb[ks & 1][t], acc[1][t], 0, 0, 0);
        }
    }

    #pragma unroll
    for (int t = 0; t < 8; t++) {
        int j = t * 16 + m;
        float bias = b1[j];
        #pragma unroll
        for (int mt = 0; mt < 2; mt++) {
            #pragma unroll
            for (int r = 0; r < 4; r++) {
                int row = mt * 16 + quad * 4 + r;
                h_lds[wave][row][j] = f2b(fmaxf(acc[mt][t][r] + bias, 0.0f));
            }
        }
    }
    // h_lds[wave] is wave-private — per-wave LDS drain instead of barrier.
    asm volatile("s_waitcnt lgkmcnt(0)" ::: "memory");

    // ---- Layer 2: load all 8 h-fragments from LDS, double-buffer W2 loads.
    short8 h0[4], h1[4];
    #pragma unroll
    for (int ks = 0; ks < 4; ks++) {
        int k0 = ks * 32 + quad * 8;
        h0[ks] = *(const short8*)&h_lds[wave][m][k0];
        h1[ks] = *(const short8*)&h_lds[wave][16 + m][k0];
    }

    floatx4 acc2[2][4], acc3[2][4];
    #pragma unroll
    for (int mt = 0; mt < 2; mt++)
        #pragma unroll
        for (int t = 0; t < 4; t++) { acc2[mt][t] = (floatx4)(0.0f); acc3[mt][t] = (floatx4)(0.0f); }

    const unsigned short* W2lp = W2lf + (lane << 3);
    const unsigned short* W2rp = W2rf + (lane << 3);
    short8 bl2[2][4], br2[2][4];
    #pragma unroll
    for (int t = 0; t < 4; t++) {
        bl2[0][t] = *(const short8*)(W2lp + ((t * 64) << 3));
        br2[0][t] = *(const short8*)(W2rp + ((t * 64) << 3));
    }

    #pragma unroll
    for (int ks = 0; ks < 4; ks++) {
        if (ks < 3) {
            #pragma unroll
            for (int t = 0; t < 4; t++) {
                bl2[(ks + 1) & 1][t] = *(const short8*)(W2lp + ((((ks + 1) * 4 + t) * 64) << 3));
                br2[(ks + 1) & 1][t] = *(const short8*)(W2rp + ((((ks + 1) * 4 + t) * 64) << 3));
            }
        }
        #pragma unroll
        for (int t = 0; t < 4; t++) {
            acc2[0][t] = __builtin_amdgcn_mfma_f32_16x16x32_bf16(h0[ks], bl2[ks & 1][t], acc2[0][t], 0, 0, 0);
            acc2[1][t] = __builtin_amdgcn_mfma_f32_16x16x32_bf16(h1[ks], bl2[ks & 1][t], acc2[1][t], 0, 0, 0);
            acc3[0][t] = __builtin_amdgcn_mfma_f32_16x16x32_bf16(h0[ks], br2[ks & 1][t], acc3[0][t], 0, 0, 0);
            acc3[1][t] = __builtin_amdgcn_mfma_f32_16x16x32_bf16(h1[ks], br2[ks & 1][t], acc3[1][t], 0, 0, 0);
        }
    }

    // pi-layout epilogue: lane (m) owns byte/short positions m*4 + t of each
    // of its 8 rows. g2q: one u32 store (4 fp8). r2b: one u16x4 store.
    #pragma unroll
    for (int mt = 0; mt < 2; mt++) {
        #pragma unroll
        for (int r = 0; r < 4; r++) {
            int n = node0 + mt * 16 + quad * 4 + r;
            if (n < N_NODES) {
                int p = 0;
                p = __builtin_amdgcn_cvt_pk_fp8_f32(acc2[mt][0][r], acc2[mt][1][r], p, false);
                p = __builtin_amdgcn_cvt_pk_fp8_f32(acc2[mt][2][r], acc2[mt][3][r], p, true);
                *(unsigned int*)(g2q + (size_t)n * 64 + m * 4) = (unsigned int)p;
                u16x4 rb;
                rb.x = f2b(acc3[mt][0][r]);
                rb.y = f2b(acc3[mt][1][r]);
                rb.z = f2b(acc3[mt][2][r]);
                rb.w = f2b(acc3[mt][3][r]);
                *(u16x4*)(r2b + (size_t)n * 64 + m * 4) = rb;
            }
        }
    }
}

// ===========================================================================
// Layer-2 gather (fp8 rows, 64 B/edge) fused with bias + residual +
// log_softmax. Rows in pi-layout; lane q reads bytes q*8..q*8+7 = cols
// {16t+2q, 16t+2q+1}. Un-permuted at the final store.
__global__ __launch_bounds__(256) void gather_final_kernel(
    const unsigned char* __restrict__ g2q, const int* __restrict__ edge_src,
    const int2* __restrict__ nodeInfo, const unsigned short* __restrict__ r2b,
    const float* __restrict__ b2, float* __restrict__ out)
{
    int tid = blockIdx.x * 256 + threadIdx.x;
    int node = tid >> 3;
    int q = tid & 7;
    int2 info = nodeInfo[node];
    int e = info.x, deg = info.y, end = info.x + deg;
    const uint2* f8 = (const uint2*)g2q;      // 8 fp8 per uint2; row = 8 uint2
    float acc[8];
    #pragma unroll
    for (int j = 0; j < 8; j++) acc[j] = 0.0f;

    #define ACC8(W)  do {                                                    \
        floatx2 p;                                                           \
        p = __builtin_amdgcn_cvt_pk_f32_fp8((W).x, false); acc[0]+=p.x; acc[1]+=p.y; \
        p = __builtin_amdgcn_cvt_pk_f32_fp8((W).x, true);  acc[2]+=p.x; acc[3]+=p.y; \
        p = __builtin_amdgcn_cvt_pk_f32_fp8((W).y, false); acc[4]+=p.x; acc[5]+=p.y; \
        p = __builtin_amdgcn_cvt_pk_f32_fp8((W).y, true);  acc[6]+=p.x; acc[7]+=p.y; \
    } while (0)

    for (; e + 4 <= end; e += 4) {
        int s0 = edge_src[e + 0];
        int s1 = edge_src[e + 1];
        int s2 = edge_src[e + 2];
        int s3 = edge_src[e + 3];
        uint2 v0 = f8[(size_t)s0 * 8 + q];
        uint2 v1 = f8[(size_t)s1 * 8 + q];
        uint2 v2 = f8[(size_t)s2 * 8 + q];
        uint2 v3 = f8[(size_t)s3 * 8 + q];
        ACC8(v0); ACC8(v1); ACC8(v2); ACC8(v3);
    }
    for (; e < end; e++) {
        uint2 v0 = f8[(size_t)edge_src[e] * 8 + q];
        ACC8(v0);
    }
    #undef ACC8

    float inv = (deg > 0) ? 1.0f / (float)deg : 0.0f;

    // residual: r2b is in the same pi-layout -> contiguous u16x8 per lane
    u16x8 rv = ((const u16x8*)r2b)[tid];            // node*64 + q*8 .. +7

    // bias for position q*8+j: col = 16*(j&3) + 2q + (j>>2)
    float2 bb0 = *(const float2*)(b2 + 0  + 2 * q);
    float2 bb1 = *(const float2*)(b2 + 16 + 2 * q);
    float2 bb2 = *(const float2*)(b2 + 32 + 2 * q);
    float2 bb3 = *(const float2*)(b2 + 48 + 2 * q);

    float v[8];
    v[0] = acc[0] * inv + bb0.x + b2f(rv[0]);
    v[1] = acc[1] * inv + bb1.x + b2f(rv[1]);
    v[2] = acc[2] * inv + bb2.x + b2f(rv[2]);
    v[3] = acc[3] * inv + bb3.x + b2f(rv[3]);
    v[4] = acc[4] * inv + bb0.y + b2f(rv[4]);
    v[5] = acc[5] * inv + bb1.y + b2f(rv[5]);
    v[6] = acc[6] * inv + bb2.y + b2f(rv[6]);
    v[7] = acc[7] * inv + bb3.y + b2f(rv[7]);

    float mx = v[0];
    #pragma unroll
    for (int j = 1; j < 8; j++) mx = fmaxf(mx, v[j]);
    mx = fmaxf(mx, __shfl_xor(mx, 1, 64));
    mx = fmaxf(mx, __shfl_xor(mx, 2, 64));
    mx = fmaxf(mx, __shfl_xor(mx, 4, 64));
    float s = 0.0f;
    #pragma unroll
    for (int j = 0; j < 8; j++) s += expf(v[j] - mx);
    s += __shfl_xor(s, 1, 64);
    s += __shfl_xor(s, 2, 64);
    s += __shfl_xor(s, 4, 64);
    float lg = mx + logf(s);

    // un-permute: v[t], v[t+4] are cols 16t+2q, 16t+2q+1 -> float2 stores
    float* ob = out + (size_t)node * 64 + 2 * q;
    *(float2*)(ob + 0)  = make_float2(v[0] - lg, v[4] - lg);
    *(float2*)(ob + 16) = make_float2(v[1] - lg, v[5] - lg);
    *(float2*)(ob + 32) = make_float2(v[2] - lg, v[6] - lg);
    *(float2*)(ob + 48) = make_float2(v[3] - lg, v[7] - lg);
}

// ===========================================================================
extern "C" void kernel_launch(void* const* d_in, const int* in_sizes, int n_in,
                              void* d_out, int out_size, void* d_ws, size_t ws_size,
                              hipStream_t stream)
{
    const float* x   = (const float*)d_in[0];
    const int*   ei  = (const int*)d_in[1];
    const float* W1l = (const float*)d_in[2];
    const float* b1  = (const float*)d_in[3];
    const float* W1r = (const float*)d_in[4];
    const float* W2l = (const float*)d_in[5];
    const float* b2  = (const float*)d_in[6];
    const float* W2r = (const float*)d_in[7];
    float* out = (float*)d_out;

    int E = in_sizes[1] / 2;
    const int* src = ei;
    const int* dst = ei + E;

    // Per-bucket pair capacity: 1.5x mean (mean 6400, sigma 80 -> +40 sigma).
    int pairCap = ((E / NBUCKET) * 3 / 2 + 255) / 256 * 256;   // 9600 for E=1.6M

    // Workspace layout (16B-aligned sections)
    char* ws = (char*)d_ws;
    int*  bucketCursor = (int*)ws;   ws += ((size_t)NBUCKET * 4 + 15) / 16 * 16;
    int2* pairs        = (int2*)ws;  ws += (size_t)NBUCKET * pairCap * 8;
    int*  edge_src     = (int*)ws;   ws += (size_t)NBUCKET * pairCap * 4;
    int2* nodeInfo     = (int2*)ws;  ws += (size_t)N_NODES * 8;
    unsigned short* xb   = (unsigned short*)ws;  ws += (size_t)N_NODES * 128 * 2;
    unsigned char*  xq   = (unsigned char*)ws;   ws += (size_t)N_NODES * 128;
    unsigned short* a1b  = (unsigned short*)ws;  ws += (size_t)N_NODES * 128 * 2;
    unsigned char*  g2q  = (unsigned char*)ws;   ws += (size_t)N_NODES * 64;
    unsigned short* r2b  = (unsigned short*)ws;  ws += (size_t)N_NODES * 64 * 2;
    unsigned short* Wc1f = (unsigned short*)ws;  ws += 128 * 256 * 2;
    unsigned short* W2lf = (unsigned short*)ws;  ws += 64 * 128 * 2;
    unsigned short* W2rf = (unsigned short*)ws;  ws += 64 * 128 * 2;

    // 1. prep: bf16 + 32-B-slice fp8 casts + weight swizzle + cursor init
    prep_kernel<<<12693, 256, 0, stream>>>(
        x, W1l, W1r, W2l, W2r, xb, xq, Wc1f, W2lf, W2rf, bucketCursor, pairCap);

    // 2. bucket edges by dst range (block-exclusive chunk writes)
    {
        const int EPB = 1024 * BK_EPT;
        bucket_kernel<<<(E + EPB - 1) / EPB, 1024, 0, stream>>>(
            src, dst, bucketCursor, pairs, E);
    }

    // 3. per-bucket LDS hist/scan/place -> edge_src + nodeInfo (beg,deg)
    fill_kernel<<<NBUCKET, 1024, 0, stream>>>(
        pairs, bucketCursor, edge_src, nodeInfo, pairCap);

    // 4. layer-1 aggregation, 32-B XCD slices x 2 lanes/node
    gather_fp8_kernel<<<GFP8_GRID, 256, 0, stream>>>(
        xq, edge_src, nodeInfo, a1b);

    // 5. fused dense block: layer1 GEMM + relu + both layer2 matmuls
    fused_l1_kernel<<<(N_NODES + 127) / 128, 256, 0, stream>>>(
        a1b, xb, Wc1f, b1, W2lf, W2rf, g2q, r2b);

    // 6. layer-2 aggregation (fp8) fused with bias + residual + log_softmax
    gather_final_kernel<<<(N_NODES * 8) / 256, 256, 0, stream>>>(
        g2q, edge_src, nodeInfo, r2b, b2, out);
}

// Round 8
// 252.078 us; speedup vs baseline: 1.1150x; 1.0441x over previous
//
#include <hip/hip_runtime.h>
#include <hip/hip_bf16.h>

#define N_NODES 100000
#define NBUCKET 250
#define BUCKET_W 400              // nodes per dst-bucket (N_NODES/NBUCKET exact)
#define BK_EPT 14                 // edges per thread in bucket pass
#define XCAST_BLOCKS 3125         // N_NODES*128 floats / 4 / 1024 threads
#define WPREP_BLOCKS 48           // 49152 weight units / 1024

typedef __attribute__((ext_vector_type(8))) short short8;     // 8 bf16 (4 VGPRs)
typedef __attribute__((ext_vector_type(8))) unsigned short u16x8;
typedef __attribute__((ext_vector_type(4))) unsigned short u16x4;
typedef __attribute__((ext_vector_type(4))) float floatx4;
typedef __attribute__((ext_vector_type(2))) float floatx2;

__device__ __forceinline__ float b2f(unsigned short u) {
    return __uint_as_float(((unsigned int)u) << 16);
}
__device__ __forceinline__ unsigned short f2b(float f) {   // RNE
    unsigned int u = __float_as_uint(f);
    unsigned int r = u + 0x7FFFu + ((u >> 16) & 1u);
    return (unsigned short)(r >> 16);
}

// ===========================================================================
// R16 merged prep + bucket kernel. The two are data-independent (prep reads
// x/W; bucket reads edge_index) but were serialized as separate launches.
// Block roles by blockIdx range:
//   [0, nbBucket)                     : edge bucketing (1024 thr, LDS hist)
//   [nbBucket, nbBucket+3125)         : x -> bf16 + fp8 e4m3 casts (node-major)
//   [nbBucket+3125, +48)              : fragment-major weight swizzle
// bucketCursor is zeroed via hipMemsetAsync before launch; it now holds pure
// per-bucket edge counts (pairs index = bk*pairCap + base + rank).
__global__ __launch_bounds__(1024) void prep_bucket_kernel(
    const float* __restrict__ x,
    const float* __restrict__ W1l, const float* __restrict__ W1r,
    const float* __restrict__ W2l, const float* __restrict__ W2r,
    unsigned short* __restrict__ xb, unsigned char* __restrict__ xq,
    unsigned short* __restrict__ Wc1f,
    unsigned short* __restrict__ W2lf, unsigned short* __restrict__ W2rf,
    const int* __restrict__ src, const int* __restrict__ dst,
    int* __restrict__ bucketCursor, int2* __restrict__ pairs,
    int E, int nbBucket, int pairCap)
{
    int blk = blockIdx.x;
    if (blk < nbBucket) {
        // ---- bucket pass (block-exclusive edge chunk) ----
        __shared__ int cnt[NBUCKET];
        __shared__ int base[NBUCKET];
        const int EPB = 1024 * BK_EPT;
        int e0 = blk * EPB;
        for (int t = threadIdx.x; t < NBUCKET; t += 1024) cnt[t] = 0;
        __syncthreads();

        int es[BK_EPT], ed[BK_EPT], rk[BK_EPT], bk[BK_EPT];
        #pragma unroll
        for (int j = 0; j < BK_EPT; j++) {
            int i = e0 + j * 1024 + threadIdx.x;
            if (i < E) {
                es[j] = src[i];
                ed[j] = dst[i];
                bk[j] = ed[j] / BUCKET_W;
                rk[j] = atomicAdd(&cnt[bk[j]], 1);
            } else {
                bk[j] = -1;
            }
        }
        __syncthreads();
        for (int t = threadIdx.x; t < NBUCKET; t += 1024)
            base[t] = atomicAdd(&bucketCursor[t], cnt[t]);
        __syncthreads();

        #pragma unroll
        for (int j = 0; j < BK_EPT; j++) {
            if (bk[j] >= 0)
                pairs[(size_t)bk[j] * pairCap + base[bk[j]] + rk[j]] =
                    make_int2(es[j], ed[j]);
        }
    } else if (blk < nbBucket + XCAST_BLOCKS) {
        // ---- x -> bf16 + fp8 (node-major: xq[node][128B]) ----
        int tid = (blk - nbBucket) * 1024 + threadIdx.x;   // one float4 each
        float4 v = ((const float4*)x)[tid];
        u16x4 o;
        o.x = f2b(v.x); o.y = f2b(v.y); o.z = f2b(v.z); o.w = f2b(v.w);
        ((u16x4*)xb)[tid] = o;
        int p = 0;
        p = __builtin_amdgcn_cvt_pk_fp8_f32(v.x, v.y, p, false);  // bytes 0,1
        p = __builtin_amdgcn_cvt_pk_fp8_f32(v.z, v.w, p, true);   // bytes 2,3
        ((unsigned int*)xq)[tid] = (unsigned int)p;
    } else {
        // ---- fragment-major weight swizzle ----
        int tid = (blk - nbBucket - XCAST_BLOCKS) * 1024 + threadIdx.x;
        if (tid < 32768) {                 // 8 ks * 8 t * 64 lane * 8 j
            int j = tid & 7, lane = (tid >> 3) & 63, t = (tid >> 9) & 7, ks = tid >> 12;
            int m = lane & 15, quad = lane >> 4;
            int row = t * 16 + m;
            int k = ks * 32 + quad * 8 + j;
            float v = (k < 128) ? W1l[row * 128 + k] : W1r[row * 128 + (k - 128)];
            Wc1f[tid] = f2b(v);
        } else if (tid < 40960) {          // 4 ks * 4 t * 64 lane * 8 j
            int idx = tid - 32768;
            int j = idx & 7, lane = (idx >> 3) & 63, t = (idx >> 9) & 3, ks = idx >> 11;
            int m = lane & 15, quad = lane >> 4;
            int row = t * 16 + m;
            int k = ks * 32 + quad * 8 + j;
            W2lf[idx] = f2b(W2l[row * 128 + k]);
        } else if (tid < 49152) {
            int idx = tid - 40960;
            int j = idx & 7, lane = (idx >> 3) & 63, t = (idx >> 9) & 3, ks = idx >> 11;
            int m = lane & 15, quad = lane >> 4;
            int row = t * 16 + m;
            int k = ks * 32 + quad * 8 + j;
            W2rf[idx] = f2b(W2r[row * 128 + k]);
        }
    }
}

// ===========================================================================
// Pass 2: one block per bucket. LDS hist over 400 nodes, LDS scan, cursors ->
// edge_src + nodeInfo (beg,deg). bucketCursor[b] now holds the plain count.
__global__ __launch_bounds__(1024) void fill_kernel(
    const int2* __restrict__ pairs, const int* __restrict__ bucketCursor,
    int* __restrict__ edge_src, int2* __restrict__ nodeInfo, int pairCap)
{
    __shared__ int hist[BUCKET_W];
    __shared__ int off[BUCKET_W];
    __shared__ int cur[BUCKET_W];
    int b = blockIdx.x;
    int t = threadIdx.x;
    int base = b * pairCap;
    int cnt = bucketCursor[b];
    int node0 = b * BUCKET_W;

    if (t < BUCKET_W) hist[t] = 0;
    __syncthreads();
    for (int i = t; i < cnt; i += 1024)
        atomicAdd(&hist[pairs[base + i].y - node0], 1);
    __syncthreads();

    if (t < BUCKET_W) off[t] = hist[t];
    __syncthreads();
    for (int o = 1; o < BUCKET_W; o <<= 1) {
        int v = 0;
        if (t < BUCKET_W && t >= o) v = off[t - o];
        __syncthreads();
        if (t < BUCKET_W && t >= o) off[t] += v;
        __syncthreads();
    }
    if (t < BUCKET_W) {
        int gb = base + off[t] - hist[t];     // exclusive prefix
        cur[t] = gb;
        nodeInfo[node0 + t] = make_int2(gb, hist[t]);
    }
    __syncthreads();

    for (int i = t; i < cnt; i += 1024) {
        int2 p = pairs[base + i];
        int pos = atomicAdd(&cur[p.y - node0], 1);
        edge_src[pos] = p.x;
    }
}

// ===========================================================================
// Layer-1 gather, node-major fp8 rows (reverted to R4 — the empirical floor).
// Cross-round evidence: node-major 128-B rows (R4, 52.8 us, 3.4 TB/s HBM),
// 16-B XCD slices (R6, 74.5 us) and 32-B slices (R7, 57.4 us) all saturate
// ~3.6-3.9 TB/s of 16-B lane requests — the divergent-gather request path is
// the invariant limiter, and node-major minimizes per-edge overhead.
__global__ __launch_bounds__(256) void gather_fp8_kernel(
    const unsigned char* __restrict__ xq, const int* __restrict__ edge_src,
    const int2* __restrict__ nodeInfo, unsigned short* __restrict__ aggOut)
{
    int tid = blockIdx.x * 256 + threadIdx.x;
    int node = tid >> 3;
    int q = tid & 7;
    int2 info = nodeInfo[node];
    int e = info.x, deg = info.y, end = info.x + deg;
    const uint4* f16 = (const uint4*)xq;      // 16 fp8 per uint4

    float acc[16];
    #pragma unroll
    for (int j = 0; j < 16; j++) acc[j] = 0.0f;

    #define ACC16(W)  do {                                                   \
        floatx2 p;                                                           \
        p = __builtin_amdgcn_cvt_pk_f32_fp8((W).x, false); acc[0]+=p.x; acc[1]+=p.y;  \
        p = __builtin_amdgcn_cvt_pk_f32_fp8((W).x, true);  acc[2]+=p.x; acc[3]+=p.y;  \
        p = __builtin_amdgcn_cvt_pk_f32_fp8((W).y, false); acc[4]+=p.x; acc[5]+=p.y;  \
        p = __builtin_amdgcn_cvt_pk_f32_fp8((W).y, true);  acc[6]+=p.x; acc[7]+=p.y;  \
        p = __builtin_amdgcn_cvt_pk_f32_fp8((W).z, false); acc[8]+=p.x; acc[9]+=p.y;  \
        p = __builtin_amdgcn_cvt_pk_f32_fp8((W).z, true);  acc[10]+=p.x; acc[11]+=p.y;\
        p = __builtin_amdgcn_cvt_pk_f32_fp8((W).w, false); acc[12]+=p.x; acc[13]+=p.y;\
        p = __builtin_amdgcn_cvt_pk_f32_fp8((W).w, true);  acc[14]+=p.x; acc[15]+=p.y;\
    } while (0)

    for (; e + 4 <= end; e += 4) {
        int s0 = edge_src[e + 0];
        int s1 = edge_src[e + 1];
        int s2 = edge_src[e + 2];
        int s3 = edge_src[e + 3];
        uint4 w0 = f16[(size_t)s0 * 8 + q];
        uint4 w1 = f16[(size_t)s1 * 8 + q];
        uint4 w2 = f16[(size_t)s2 * 8 + q];
        uint4 w3 = f16[(size_t)s3 * 8 + q];
        ACC16(w0); ACC16(w1); ACC16(w2); ACC16(w3);
    }
    for (; e < end; e++) {
        uint4 w0 = f16[(size_t)edge_src[e] * 8 + q];
        ACC16(w0);
    }
    #undef ACC16

    float inv = (deg > 0) ? 1.0f / (float)deg : 0.0f;
    u16x8 o0, o1;
    #pragma unroll
    for (int j = 0; j < 8; j++) { o0[j] = f2b(acc[j] * inv); o1[j] = f2b(acc[8 + j] * inv); }
    u16x8* op = (u16x8*)(aggOut + (size_t)node * 128 + q * 16);
    op[0] = o0;
    op[1] = o1;
}

// ===========================================================================
// Fused dense block (fragment-major weights, 32 nodes/wave).
// R9: deep register prefetch (all 16 A-frags up front, B double-buffered).
// R10: g2 output stored as fp8 e4m3 in pi-layout (col 16t+m -> byte m*4+t),
// r2b stored bf16 in the same pi-layout. a1b node-major (reverted with R16).
__global__ __launch_bounds__(256, 2) void fused_l1_kernel(
    const unsigned short* __restrict__ a1b, const unsigned short* __restrict__ xb,
    const unsigned short* __restrict__ Wc1f, const float* __restrict__ b1,
    const unsigned short* __restrict__ W2lf, const unsigned short* __restrict__ W2rf,
    unsigned char* __restrict__ g2q, unsigned short* __restrict__ r2b)
{
    __shared__ unsigned short h_lds[4][32][136];

    int wave = threadIdx.x >> 6;
    int lane = threadIdx.x & 63;
    int m    = lane & 15;
    int quad = lane >> 4;
    int node0 = blockIdx.x * 128 + wave * 32;

    int n0 = min(node0 + m,      N_NODES - 1);
    int n1 = min(node0 + 16 + m, N_NODES - 1);

    // ---- Layer 1: prefetch ALL 16 A-fragments (64 VGPRs, 16 loads in flight)
    short8 a0[8], a1[8];
    #pragma unroll
    for (int ks = 0; ks < 8; ks++) {
        int k0 = ks * 32 + quad * 8;
        const unsigned short* s = (ks < 4) ? a1b : xb;
        int koff = (ks < 4) ? k0 : (k0 - 128);
        a0[ks] = *(const short8*)(s + (size_t)n0 * 128 + koff);
        a1[ks] = *(const short8*)(s + (size_t)n1 * 128 + koff);
    }

    floatx4 acc[2][8];
    #pragma unroll
    for (int mt = 0; mt < 2; mt++)
        #pragma unroll
        for (int t = 0; t < 8; t++) acc[mt][t] = (floatx4)(0.0f);

    // B fragments: double-buffered, prefetched one ks-step ahead.
    const unsigned short* Wp = Wc1f + (lane << 3);
    short8 bb[2][8];
    #pragma unroll
    for (int t = 0; t < 8; t++)
        bb[0][t] = *(const short8*)(Wp + ((t * 64) << 3));

    #pragma unroll
    for (int ks = 0; ks < 8; ks++) {
        if (ks < 7) {
            #pragma unroll
            for (int t = 0; t < 8; t++)
                bb[(ks + 1) & 1][t] =
                    *(const short8*)(Wp + ((((ks + 1) * 8 + t) * 64) << 3));
        }
        #pragma unroll
        for (int t = 0; t < 8; t++) {
            acc[0][t] = __builtin_amdgcn_mfma_f32_16x16x32_bf16(a0[ks], bb[ks & 1][t], acc[0][t], 0, 0, 0);
            acc[1][t] = __builtin_amdgcn_mfma_f32_16x16x32_bf16(a1[ks], bb[ks & 1][t], acc[1][t], 0, 0, 0);
        }
    }

    #pragma unroll
    for (int t = 0; t < 8; t++) {
        int j = t * 16 + m;
        float bias = b1[j];
        #pragma unroll
        for (int mt = 0; mt < 2; mt++) {
            #pragma unroll
            for (int r = 0; r < 4; r++) {
                int row = mt * 16 + quad * 4 + r;
                h_lds[wave][row][j] = f2b(fmaxf(acc[mt][t][r] + bias, 0.0f));
            }
        }
    }
    // h_lds[wave] is wave-private — per-wave LDS drain instead of barrier.
    asm volatile("s_waitcnt lgkmcnt(0)" ::: "memory");

    // ---- Layer 2: load all 8 h-fragments from LDS, double-buffer W2 loads.
    short8 h0[4], h1[4];
    #pragma unroll
    for (int ks = 0; ks < 4; ks++) {
        int k0 = ks * 32 + quad * 8;
        h0[ks] = *(const short8*)&h_lds[wave][m][k0];
        h1[ks] = *(const short8*)&h_lds[wave][16 + m][k0];
    }

    floatx4 acc2[2][4], acc3[2][4];
    #pragma unroll
    for (int mt = 0; mt < 2; mt++)
        #pragma unroll
        for (int t = 0; t < 4; t++) { acc2[mt][t] = (floatx4)(0.0f); acc3[mt][t] = (floatx4)(0.0f); }

    const unsigned short* W2lp = W2lf + (lane << 3);
    const unsigned short* W2rp = W2rf + (lane << 3);
    short8 bl2[2][4], br2[2][4];
    #pragma unroll
    for (int t = 0; t < 4; t++) {
        bl2[0][t] = *(const short8*)(W2lp + ((t * 64) << 3));
        br2[0][t] = *(const short8*)(W2rp + ((t * 64) << 3));
    }

    #pragma unroll
    for (int ks = 0; ks < 4; ks++) {
        if (ks < 3) {
            #pragma unroll
            for (int t = 0; t < 4; t++) {
                bl2[(ks + 1) & 1][t] = *(const short8*)(W2lp + ((((ks + 1) * 4 + t) * 64) << 3));
                br2[(ks + 1) & 1][t] = *(const short8*)(W2rp + ((((ks + 1) * 4 + t) * 64) << 3));
            }
        }
        #pragma unroll
        for (int t = 0; t < 4; t++) {
            acc2[0][t] = __builtin_amdgcn_mfma_f32_16x16x32_bf16(h0[ks], bl2[ks & 1][t], acc2[0][t], 0, 0, 0);
            acc2[1][t] = __builtin_amdgcn_mfma_f32_16x16x32_bf16(h1[ks], bl2[ks & 1][t], acc2[1][t], 0, 0, 0);
            acc3[0][t] = __builtin_amdgcn_mfma_f32_16x16x32_bf16(h0[ks], br2[ks & 1][t], acc3[0][t], 0, 0, 0);
            acc3[1][t] = __builtin_amdgcn_mfma_f32_16x16x32_bf16(h1[ks], br2[ks & 1][t], acc3[1][t], 0, 0, 0);
        }
    }

    // pi-layout epilogue: lane (m) owns byte/short positions m*4 + t of each
    // of its 8 rows. g2q: one u32 store (4 fp8). r2b: one u16x4 store.
    #pragma unroll
    for (int mt = 0; mt < 2; mt++) {
        #pragma unroll
        for (int r = 0; r < 4; r++) {
            int n = node0 + mt * 16 + quad * 4 + r;
            if (n < N_NODES) {
                int p = 0;
                p = __builtin_amdgcn_cvt_pk_fp8_f32(acc2[mt][0][r], acc2[mt][1][r], p, false);
                p = __builtin_amdgcn_cvt_pk_fp8_f32(acc2[mt][2][r], acc2[mt][3][r], p, true);
                *(unsigned int*)(g2q + (size_t)n * 64 + m * 4) = (unsigned int)p;
                u16x4 rb;
                rb.x = f2b(acc3[mt][0][r]);
                rb.y = f2b(acc3[mt][1][r]);
                rb.z = f2b(acc3[mt][2][r]);
                rb.w = f2b(acc3[mt][3][r]);
                *(u16x4*)(r2b + (size_t)n * 64 + m * 4) = rb;
            }
        }
    }
}

// ===========================================================================
// Layer-2 gather (fp8 rows, 64 B/edge) fused with bias + residual +
// log_softmax. Rows in pi-layout; lane q reads bytes q*8..q*8+7 = cols
// {16t+2q, 16t+2q+1}. Un-permuted at the final store.
__global__ __launch_bounds__(256) void gather_final_kernel(
    const unsigned char* __restrict__ g2q, const int* __restrict__ edge_src,
    const int2* __restrict__ nodeInfo, const unsigned short* __restrict__ r2b,
    const float* __restrict__ b2, float* __restrict__ out)
{
    int tid = blockIdx.x * 256 + threadIdx.x;
    int node = tid >> 3;
    int q = tid & 7;
    int2 info = nodeInfo[node];
    int e = info.x, deg = info.y, end = info.x + deg;
    const uint2* f8 = (const uint2*)g2q;      // 8 fp8 per uint2; row = 8 uint2
    float acc[8];
    #pragma unroll
    for (int j = 0; j < 8; j++) acc[j] = 0.0f;

    #define ACC8(W)  do {                                                    \
        floatx2 p;                                                           \
        p = __builtin_amdgcn_cvt_pk_f32_fp8((W).x, false); acc[0]+=p.x; acc[1]+=p.y; \
        p = __builtin_amdgcn_cvt_pk_f32_fp8((W).x, true);  acc[2]+=p.x; acc[3]+=p.y; \
        p = __builtin_amdgcn_cvt_pk_f32_fp8((W).y, false); acc[4]+=p.x; acc[5]+=p.y; \
        p = __builtin_amdgcn_cvt_pk_f32_fp8((W).y, true);  acc[6]+=p.x; acc[7]+=p.y; \
    } while (0)

    for (; e + 4 <= end; e += 4) {
        int s0 = edge_src[e + 0];
        int s1 = edge_src[e + 1];
        int s2 = edge_src[e + 2];
        int s3 = edge_src[e + 3];
        uint2 v0 = f8[(size_t)s0 * 8 + q];
        uint2 v1 = f8[(size_t)s1 * 8 + q];
        uint2 v2 = f8[(size_t)s2 * 8 + q];
        uint2 v3 = f8[(size_t)s3 * 8 + q];
        ACC8(v0); ACC8(v1); ACC8(v2); ACC8(v3);
    }
    for (; e < end; e++) {
        uint2 v0 = f8[(size_t)edge_src[e] * 8 + q];
        ACC8(v0);
    }
    #undef ACC8

    float inv = (deg > 0) ? 1.0f / (float)deg : 0.0f;

    // residual: r2b is in the same pi-layout -> contiguous u16x8 per lane
    u16x8 rv = ((const u16x8*)r2b)[tid];            // node*64 + q*8 .. +7

    // bias for position q*8+j: col = 16*(j&3) + 2q + (j>>2)
    float2 bb0 = *(const float2*)(b2 + 0  + 2 * q);
    float2 bb1 = *(const float2*)(b2 + 16 + 2 * q);
    float2 bb2 = *(const float2*)(b2 + 32 + 2 * q);
    float2 bb3 = *(const float2*)(b2 + 48 + 2 * q);

    float v[8];
    v[0] = acc[0] * inv + bb0.x + b2f(rv[0]);
    v[1] = acc[1] * inv + bb1.x + b2f(rv[1]);
    v[2] = acc[2] * inv + bb2.x + b2f(rv[2]);
    v[3] = acc[3] * inv + bb3.x + b2f(rv[3]);
    v[4] = acc[4] * inv + bb0.y + b2f(rv[4]);
    v[5] = acc[5] * inv + bb1.y + b2f(rv[5]);
    v[6] = acc[6] * inv + bb2.y + b2f(rv[6]);
    v[7] = acc[7] * inv + bb3.y + b2f(rv[7]);

    float mx = v[0];
    #pragma unroll
    for (int j = 1; j < 8; j++) mx = fmaxf(mx, v[j]);
    mx = fmaxf(mx, __shfl_xor(mx, 1, 64));
    mx = fmaxf(mx, __shfl_xor(mx, 2, 64));
    mx = fmaxf(mx, __shfl_xor(mx, 4, 64));
    float s = 0.0f;
    #pragma unroll
    for (int j = 0; j < 8; j++) s += expf(v[j] - mx);
    s += __shfl_xor(s, 1, 64);
    s += __shfl_xor(s, 2, 64);
    s += __shfl_xor(s, 4, 64);
    float lg = mx + logf(s);

    // un-permute: v[t], v[t+4] are cols 16t+2q, 16t+2q+1 -> float2 stores
    float* ob = out + (size_t)node * 64 + 2 * q;
    *(float2*)(ob + 0)  = make_float2(v[0] - lg, v[4] - lg);
    *(float2*)(ob + 16) = make_float2(v[1] - lg, v[5] - lg);
    *(float2*)(ob + 32) = make_float2(v[2] - lg, v[6] - lg);
    *(float2*)(ob + 48) = make_float2(v[3] - lg, v[7] - lg);
}

// ===========================================================================
extern "C" void kernel_launch(void* const* d_in, const int* in_sizes, int n_in,
                              void* d_out, int out_size, void* d_ws, size_t ws_size,
                              hipStream_t stream)
{
    const float* x   = (const float*)d_in[0];
    const int*   ei  = (const int*)d_in[1];
    const float* W1l = (const float*)d_in[2];
    const float* b1  = (const float*)d_in[3];
    const float* W1r = (const float*)d_in[4];
    const float* W2l = (const float*)d_in[5];
    const float* b2  = (const float*)d_in[6];
    const float* W2r = (const float*)d_in[7];
    float* out = (float*)d_out;

    int E = in_sizes[1] / 2;
    const int* src = ei;
    const int* dst = ei + E;

    // Per-bucket pair capacity: 1.5x mean (mean 6400, sigma 80 -> +40 sigma).
    int pairCap = ((E / NBUCKET) * 3 / 2 + 255) / 256 * 256;   // 9600 for E=1.6M

    // Workspace layout (16B-aligned sections)
    char* ws = (char*)d_ws;
    int*  bucketCursor = (int*)ws;   ws += ((size_t)NBUCKET * 4 + 15) / 16 * 16;
    int2* pairs        = (int2*)ws;  ws += (size_t)NBUCKET * pairCap * 8;
    int*  edge_src     = (int*)ws;   ws += (size_t)NBUCKET * pairCap * 4;
    int2* nodeInfo     = (int2*)ws;  ws += (size_t)N_NODES * 8;
    unsigned short* xb   = (unsigned short*)ws;  ws += (size_t)N_NODES * 128 * 2;
    unsigned char*  xq   = (unsigned char*)ws;   ws += (size_t)N_NODES * 128;
    unsigned short* a1b  = (unsigned short*)ws;  ws += (size_t)N_NODES * 128 * 2;
    unsigned char*  g2q  = (unsigned char*)ws;   ws += (size_t)N_NODES * 64;
    unsigned short* r2b  = (unsigned short*)ws;  ws += (size_t)N_NODES * 64 * 2;
    unsigned short* Wc1f = (unsigned short*)ws;  ws += 128 * 256 * 2;
    unsigned short* W2lf = (unsigned short*)ws;  ws += 64 * 128 * 2;
    unsigned short* W2rf = (unsigned short*)ws;  ws += 64 * 128 * 2;

    const int EPB = 1024 * BK_EPT;
    int nbBucket = (E + EPB - 1) / EPB;         // 112 for E=1.6M

    // 0. zero per-bucket edge counters (graph-capture-safe async memset)
    hipMemsetAsync(bucketCursor, 0, NBUCKET * sizeof(int), stream);

    // 1. merged prep + bucket (independent halves in one launch)
    prep_bucket_kernel<<<nbBucket + XCAST_BLOCKS + WPREP_BLOCKS, 1024, 0, stream>>>(
        x, W1l, W1r, W2l, W2r, xb, xq, Wc1f, W2lf, W2rf,
        src, dst, bucketCursor, pairs, E, nbBucket, pairCap);

    // 2. per-bucket LDS hist/scan/place -> edge_src + nodeInfo (beg,deg)
    fill_kernel<<<NBUCKET, 1024, 0, stream>>>(
        pairs, bucketCursor, edge_src, nodeInfo, pairCap);

    // 3. layer-1 aggregation from node-major fp8 table (D=128, 8 lanes/node)
    gather_fp8_kernel<<<(N_NODES * 8) / 256, 256, 0, stream>>>(
        xq, edge_src, nodeInfo, a1b);

    // 4. fused dense block: layer1 GEMM + relu + both layer2 matmuls
    fused_l1_kernel<<<(N_NODES + 127) / 128, 256, 0, stream>>>(
        a1b, xb, Wc1f, b1, W2lf, W2rf, g2q, r2b);

    // 5. layer-2 aggregation (fp8) fused with bias + residual + log_softmax
    gather_final_kernel<<<(N_NODES * 8) / 256, 256, 0, stream>>>(
        g2q, edge_src, nodeInfo, r2b, b2, out);
}